// Round 2
// baseline (246.264 us; speedup 1.0000x reference)
//
#include <hip/hip_runtime.h>

#define BH (512*2048)
#define BHA 1048576ull                   // 512*2048 elems (one activation plane)
#define PPLANE (512ull*8192ull)          // elems per partial plane [512][8192]
#define PLANE_BYTES (PPLANE*2ull)        // bf16
#define AB_ELEMS (2ull*512*2048)         // bf16 activations (inputs + prevstate)

typedef __attribute__((ext_vector_type(8))) short short8;
typedef __attribute__((ext_vector_type(4))) float floatx4;
typedef __attribute__((ext_vector_type(4))) unsigned int uint4v;
typedef __attribute__((ext_vector_type(8))) unsigned short ushort8v;

#define GLOAD_LDS16(g, l) __builtin_amdgcn_global_load_lds( \
    (const __attribute__((address_space(1))) unsigned int*)(g), \
    (__attribute__((address_space(3))) unsigned int*)(l), 16, 0, 0)

// pack two f32 -> two bf16 (round-half-up) in one dword (verified R2-R4)
__device__ inline unsigned pk2(float a, float b){
    unsigned ua = __builtin_bit_cast(unsigned, a) + 0x8000u;
    unsigned ub = __builtin_bit_cast(unsigned, b) + 0x8000u;
    return __builtin_amdgcn_perm(ub, ua, 0x07060302u);
}
__device__ inline unsigned short f2bf1(float x){
    return (unsigned short)((__builtin_bit_cast(unsigned, x) + 0x8000u) >> 16);
}
__device__ inline float bf2f(unsigned short s){
    return __builtin_bit_cast(float, ((unsigned)s) << 16);
}
__device__ inline int swz(int r, int g){ return r*4 + (g ^ ((r>>1)&3)); }
__device__ inline float fsig(float x){ return __builtin_amdgcn_rcpf(1.f + __expf(-x)); }
__device__ inline float ftanh(float x){ return 2.f*fsig(2.f*x) - 1.f; }

// ---------------------------------------------------------------------------
// Activation cast only (weight transpose now fused into the GEMM).
// Casts inputs (plane 0) and states[0] (plane 1) to bf16 flat. 1024 blocks.
// ---------------------------------------------------------------------------
__global__ __launch_bounds__(256) void prep_act(
    const float* __restrict__ inputs, const float* __restrict__ states,
    unsigned short* __restrict__ Ab)
{
    const size_t off = ((size_t)blockIdx.x * 256 + threadIdx.x) * 8;
    const float* src = (off < BHA) ? (inputs + off) : (states + (off - BHA));
    floatx4 v0 = *(const floatx4*)src;
    floatx4 v1 = *(const floatx4*)(src + 4);
    uint4v w;
    w.x = pk2(v0[0],v0[1]); w.y = pk2(v0[2],v0[3]);
    w.z = pk2(v1[0],v1[1]); w.w = pk2(v1[2],v1[3]);
    *(uint4v*)(Ab + off) = w;
}

// ---------------------------------------------------------------------------
// Fused GEMM: reads fp32 weights directly (no Wt prepass).
// Block 128x128, 4 waves of 64x64 (4x4 x mfma_16x16x32_bf16), BK=32,
// grid (64 n-panels, 4 m-blocks, 4 K-chunks) = same structure as before.
// A: bf16 from Ab via global_load_lds (pre-swizzled source, linear LDS dest).
// B: in-kernel transpose: each thread owns column n + two k-octets; 16 scalar
//    coalesced fp32 loads -> pk2 -> 2x ds_write_b128 (swizzled granule).
// Both LDS tiles use a 2-bit XOR granule swizzle: phys_g = g ^ ((row>>1)&3),
// making b128 frag reads/writes span all 32 banks per 8-lane group.
// T14 split: loads issued at iter top, cvt+write after the MFMAs.
// ---------------------------------------------------------------------------
__global__ __launch_bounds__(256, 3) void gemm_fused(
    const float* __restrict__ Wi, const float* __restrict__ Ui,
    const float* __restrict__ Wf, const float* __restrict__ Uf,
    const float* __restrict__ Wg, const float* __restrict__ Ug,
    const float* __restrict__ Wc, const float* __restrict__ Uc,
    const unsigned short* __restrict__ Ab, unsigned short* __restrict__ P)
{
    __shared__ unsigned short As[2][4096];   // [m 0..127][k-granule swizzled]
    __shared__ unsigned short Bs[2][4096];   // [n 0..127][k-granule swizzled]

    const int t = threadIdx.x, lane = t & 63, wave = t >> 6;
    const int nblk = blockIdx.x, gate = nblk >> 4, nb = nblk & 15;
    const int m0 = blockIdx.y * 128, z = blockIdx.z;

    // ---- B (weight) staging setup ----
    const float* Bsel;
    if (z < 2) { switch (gate){ case 0: Bsel=Wi; break; case 1: Bsel=Wf; break;
                                case 2: Bsel=Wg; break; default: Bsel=Wc; } }
    else       { switch (gate){ case 0: Bsel=Ui; break; case 1: Bsel=Uf; break;
                                case 2: Bsel=Ug; break; default: Bsel=Uc; } }
    const int n   = t & 127;             // owned B column within panel
    const int o0  = t >> 7;              // first k-octet (0/1); second = o0+2
    const int swk = (n >> 1) & 3;        // granule swizzle key for row n
    const float* Bp0 = Bsel + ((size_t)((z & 1) * 1024 + o0 * 8)) * 2048
                            + nb * 128 + n;
    const float* Bp1 = Bp0 + (size_t)16 * 2048;   // octet o0+2

    // ---- A staging setup (global_load_lds, pre-swizzled source) ----
    const unsigned short* Abase = Ab + (size_t)(z >> 1) * BHA
                                     + (size_t)m0 * 2048 + (z & 1) * 1024;
    const int i0 = wave * 2, i1 = wave * 2 + 1;
    const int arow = lane >> 2;
    const int agr  = (lane & 3) ^ ((lane >> 3) & 3);   // logical granule to fetch
    const unsigned short* ag0 = Abase + (size_t)(i0*16 + arow) * 2048 + agr * 8;
    const unsigned short* ag1 = Abase + (size_t)(i1*16 + arow) * 2048 + agr * 8;

    floatx4 acc[4][4];
    #pragma unroll
    for (int i = 0; i < 4; i++)
        #pragma unroll
        for (int j = 0; j < 4; j++)
            acc[i][j] = (floatx4){0.f,0.f,0.f,0.f};

    const int wm = (wave & 1) * 64, wn = (wave >> 1) * 64;
    const int row16 = lane & 15, g4 = lane >> 4;
    const int fgx = ((g4 ^ ((row16 >> 1) & 3)) << 3);  // swizzled frag granule off

    // B LDS write offsets (shorts): phys granule = octet ^ swk
    const int wb0 = n * 32 + (((o0    ) ^ swk) << 3);
    const int wb1 = n * 32 + (((o0 + 2) ^ swk) << 3);

    float u0[8], u1[8];

    // ---- prologue: tile 0 ----
    GLOAD_LDS16(ag0, &As[0][i0 * 512]);
    GLOAD_LDS16(ag1, &As[0][i1 * 512]);
    #pragma unroll
    for (int j = 0; j < 8; j++) u0[j] = Bp0[(size_t)j * 2048];
    #pragma unroll
    for (int j = 0; j < 8; j++) u1[j] = Bp1[(size_t)j * 2048];
    *(uint4v*)&Bs[0][wb0] = (uint4v){pk2(u0[0],u0[1]), pk2(u0[2],u0[3]),
                                     pk2(u0[4],u0[5]), pk2(u0[6],u0[7])};
    *(uint4v*)&Bs[0][wb1] = (uint4v){pk2(u1[0],u1[1]), pk2(u1[2],u1[3]),
                                     pk2(u1[4],u1[5]), pk2(u1[6],u1[7])};
    __syncthreads();

    for (int kk = 0; kk < 32; kk++) {
        const int cur = kk & 1;
        if (kk < 31) {                       // issue next tile's loads early
            const int nxt = cur ^ 1;
            GLOAD_LDS16(ag0 + (kk+1)*32, &As[nxt][i0 * 512]);
            GLOAD_LDS16(ag1 + (kk+1)*32, &As[nxt][i1 * 512]);
            const float* q0 = Bp0 + (size_t)(kk+1) * 65536;
            const float* q1 = Bp1 + (size_t)(kk+1) * 65536;
            #pragma unroll
            for (int j = 0; j < 8; j++) u0[j] = q0[(size_t)j * 2048];
            #pragma unroll
            for (int j = 0; j < 8; j++) u1[j] = q1[(size_t)j * 2048];
        }
        short8 afr[4], bfr[4];
        #pragma unroll
        for (int mi = 0; mi < 4; mi++)
            afr[mi] = *(const short8*)&As[cur][(wm + mi*16 + row16)*32 + fgx];
        #pragma unroll
        for (int ni = 0; ni < 4; ni++)
            bfr[ni] = *(const short8*)&Bs[cur][(wn + ni*16 + row16)*32 + fgx];
        #pragma unroll
        for (int mi = 0; mi < 4; mi++)
            #pragma unroll
            for (int ni = 0; ni < 4; ni++)
                acc[mi][ni] = __builtin_amdgcn_mfma_f32_16x16x32_bf16(
                    afr[mi], bfr[ni], acc[mi][ni], 0, 0, 0);
        if (kk < 31) {                       // cvt + transposed write, late
            const int nxt = cur ^ 1;
            *(uint4v*)&Bs[nxt][wb0] = (uint4v){pk2(u0[0],u0[1]), pk2(u0[2],u0[3]),
                                               pk2(u0[4],u0[5]), pk2(u0[6],u0[7])};
            *(uint4v*)&Bs[nxt][wb1] = (uint4v){pk2(u1[0],u1[1]), pk2(u1[2],u1[3]),
                                               pk2(u1[4],u1[5]), pk2(u1[6],u1[7])};
        }
        __syncthreads();                     // drains DMA (vmcnt) + barrier
    }

    unsigned short* dst = P + (size_t)z * PPLANE;
    const int gbase = gate * 2048 + nb * 128;
    #pragma unroll
    for (int mi = 0; mi < 4; mi++)
        #pragma unroll
        for (int ni = 0; ni < 4; ni++)
            #pragma unroll
            for (int j = 0; j < 4; j++) {
                int row = m0 + wm + mi*16 + g4*4 + j;
                int col = gbase + wn + ni*16 + row16;
                dst[(size_t)row * 8192 + col] = f2bf1(acc[mi][ni][j]);
            }
}

// ---------------------------------------------------------------------------
// Fallback GEMM (fused fp32 staging) for small ws_size.
// ---------------------------------------------------------------------------
__global__ __launch_bounds__(256, 2) void gemm_tile(
    const float* __restrict__ inputs, const float* __restrict__ states,
    const float* __restrict__ Wi, const float* __restrict__ Ui,
    const float* __restrict__ Wf, const float* __restrict__ Uf,
    const float* __restrict__ Wg, const float* __restrict__ Ug,
    const float* __restrict__ Wc, const float* __restrict__ Uc,
    unsigned short* __restrict__ P, int KB)
{
    __shared__ uint4v As[2][512];
    __shared__ uint4v Bs[2][512];

    const int t = threadIdx.x;
    const int m0 = blockIdx.y * 128;
    const int z = blockIdx.z;
    const int nblk = blockIdx.x;
    const int gate = nblk >> 4;
    const int c0 = (nblk & 15) * 128;
    const int gk = z * KB;

    const float* Abase; const float* Bsel; int ko;
    if (gk < 2048) {
        Abase = inputs; ko = gk;
        switch (gate){ case 0: Bsel=Wi; break; case 1: Bsel=Wf; break;
                       case 2: Bsel=Wg; break; default: Bsel=Wc; }
    } else {
        Abase = states; ko = gk - 2048;
        switch (gate){ case 0: Bsel=Ui; break; case 1: Bsel=Uf; break;
                       case 2: Bsel=Ug; break; default: Bsel=Uc; }
    }
    const int NIT = KB >> 5;

    const int lane = t & 63, wave = t >> 6;
    const int wm = (wave & 1) * 64, wn = (wave >> 1) * 64;
    const int row16 = lane & 15, g4 = lane >> 4;
    const int ar = t >> 2, ag = t & 3;
    const int bn = t & 127, bg2 = (t >> 7) * 2;

    const float* Ap = Abase + (size_t)(m0 + ar) * 2048 + ko + ag * 8;
    const float* Bp = Bsel + (size_t)ko * 2048 + c0 + bn;

    floatx4 acc[4][4];
    #pragma unroll
    for (int i = 0; i < 4; i++)
        #pragma unroll
        for (int j = 0; j < 4; j++)
            acc[i][j] = (floatx4){0.f,0.f,0.f,0.f};

    floatx4 a0,a1,a2,a3; float b0[8], b1[8];
    a0 = *(const floatx4*)Ap;             a1 = *(const floatx4*)(Ap + 4);
    a2 = *(const floatx4*)(Ap + 64*2048); a3 = *(const floatx4*)(Ap + 64*2048 + 4);
    #pragma unroll
    for (int j = 0; j < 8; j++) b0[j] = Bp[(size_t)(bg2*8 + j) * 2048];
    #pragma unroll
    for (int j = 0; j < 8; j++) b1[j] = Bp[(size_t)(bg2*8 + 8 + j) * 2048];
    {
        uint4v w;
        w.x=pk2(a0[0],a0[1]); w.y=pk2(a0[2],a0[3]); w.z=pk2(a1[0],a1[1]); w.w=pk2(a1[2],a1[3]);
        As[0][swz(ar, ag)] = w;
        w.x=pk2(a2[0],a2[1]); w.y=pk2(a2[2],a2[3]); w.z=pk2(a3[0],a3[1]); w.w=pk2(a3[2],a3[3]);
        As[0][swz(ar+64, ag)] = w;
        w.x=pk2(b0[0],b0[1]); w.y=pk2(b0[2],b0[3]); w.z=pk2(b0[4],b0[5]); w.w=pk2(b0[6],b0[7]);
        Bs[0][swz(bn, bg2)] = w;
        w.x=pk2(b1[0],b1[1]); w.y=pk2(b1[2],b1[3]); w.z=pk2(b1[4],b1[5]); w.w=pk2(b1[6],b1[7]);
        Bs[0][swz(bn, bg2+1)] = w;
    }

    for (int kk = 0; kk < NIT; kk++) {
        __syncthreads();
        const int cur = kk & 1;
        if (kk + 1 < NIT) {
            const float* ap = Ap + (kk+1) * 32;
            a0 = *(const floatx4*)ap;             a1 = *(const floatx4*)(ap + 4);
            a2 = *(const floatx4*)(ap + 64*2048); a3 = *(const floatx4*)(ap + 64*2048 + 4);
            const float* bp = Bp + (size_t)(kk+1) * 32 * 2048;
            #pragma unroll
            for (int j = 0; j < 8; j++) b0[j] = bp[(size_t)(bg2*8 + j) * 2048];
            #pragma unroll
            for (int j = 0; j < 8; j++) b1[j] = bp[(size_t)(bg2*8 + 8 + j) * 2048];
        }
        short8 afr[4], bfr[4];
        #pragma unroll
        for (int mi = 0; mi < 4; mi++)
            afr[mi] = *(const short8*)&As[cur][swz(wm + mi*16 + row16, g4)];
        #pragma unroll
        for (int ni = 0; ni < 4; ni++)
            bfr[ni] = *(const short8*)&Bs[cur][swz(wn + ni*16 + row16, g4)];
        #pragma unroll
        for (int mi = 0; mi < 4; mi++)
            #pragma unroll
            for (int ni = 0; ni < 4; ni++)
                acc[mi][ni] = __builtin_amdgcn_mfma_f32_16x16x32_bf16(
                    afr[mi], bfr[ni], acc[mi][ni], 0, 0, 0);
        if (kk + 1 < NIT) {
            const int nxt = cur ^ 1;
            uint4v w;
            w.x=pk2(a0[0],a0[1]); w.y=pk2(a0[2],a0[3]); w.z=pk2(a1[0],a1[1]); w.w=pk2(a1[2],a1[3]);
            As[nxt][swz(ar, ag)] = w;
            w.x=pk2(a2[0],a2[1]); w.y=pk2(a2[2],a2[3]); w.z=pk2(a3[0],a3[1]); w.w=pk2(a3[2],a3[3]);
            As[nxt][swz(ar+64, ag)] = w;
            w.x=pk2(b0[0],b0[1]); w.y=pk2(b0[2],b0[3]); w.z=pk2(b0[4],b0[5]); w.w=pk2(b0[6],b0[7]);
            Bs[nxt][swz(bn, bg2)] = w;
            w.x=pk2(b1[0],b1[1]); w.y=pk2(b1[2],b1[3]); w.z=pk2(b1[4],b1[5]); w.w=pk2(b1[6],b1[7]);
            Bs[nxt][swz(bn, bg2+1)] = w;
        }
    }

    unsigned short* dst = P + (size_t)z * PPLANE;
    const int gbase = gate * 2048 + c0;
    #pragma unroll
    for (int mi = 0; mi < 4; mi++)
        #pragma unroll
        for (int ni = 0; ni < 4; ni++)
            #pragma unroll
            for (int j = 0; j < 4; j++) {
                int row = m0 + wm + mi*16 + g4*4 + j;
                int col = gbase + wn + ni*16 + row16;
                dst[(size_t)row * 8192 + col] = f2bf1(acc[mi][ni][j]);
            }
}

// activations + LSTM combine
__global__ __launch_bounds__(256) void combine_kernel(
    float* __restrict__ out, const unsigned short* __restrict__ P,
    const float* __restrict__ states,
    const float* __restrict__ bi, const float* __restrict__ bfv,
    const float* __restrict__ bg, const float* __restrict__ bc, int nz)
{
    const int idx = (blockIdx.x * 256 + threadIdx.x) * 8;
    const int row = idx >> 11;
    const int h = idx & 2047;
    const size_t base = (size_t)row * 8192 + h;

    float xi[8], xf[8], xg[8], xc[8];
    #pragma unroll
    for (int e = 0; e < 8; e++) {
        xi[e] = bi[h+e]; xf[e] = bfv[h+e]; xg[e] = bg[h+e]; xc[e] = bc[h+e];
    }
    for (int z = 0; z < nz; z++) {
        const unsigned short* Pz = P + (size_t)z * PPLANE;
        ushort8v vi = *(const ushort8v*)&Pz[base];
        ushort8v vf = *(const ushort8v*)&Pz[base + 2048];
        ushort8v vg = *(const ushort8v*)&Pz[base + 4096];
        ushort8v vc = *(const ushort8v*)&Pz[base + 6144];
        #pragma unroll
        for (int e = 0; e < 8; e++) {
            xi[e] += bf2f(vi[e]); xf[e] += bf2f(vf[e]);
            xg[e] += bf2f(vg[e]); xc[e] += bf2f(vc[e]);
        }
    }

    const float* po = states + BH;
    floatx4 pov[2];
    pov[0] = *(const floatx4*)&po[idx];
    pov[1] = *(const floatx4*)&po[idx + 4];

    floatx4 vcv[2], vsv[2];
    #pragma unroll
    for (int q = 0; q < 2; q++)
        #pragma unroll
        for (int j = 0; j < 4; j++) {
            int e = q*4 + j;
            float c = fsig(xf[e]) * pov[q][j] + fsig(xi[e]) * ftanh(xc[e]);
            vcv[q][j] = c;
            vsv[q][j] = fsig(xg[e]) * ftanh(c);
        }
    #pragma unroll
    for (int q = 0; q < 2; q++) {
        *(floatx4*)&out[idx + q*4]        = vcv[q];
        *(floatx4*)&out[BH + idx + q*4]   = vsv[q];
        *(floatx4*)&out[2*BH + idx + q*4] = vcv[q];
    }
}

extern "C" void kernel_launch(void* const* d_in, const int* in_sizes, int n_in,
                              void* d_out, int out_size, void* d_ws, size_t ws_size,
                              hipStream_t stream) {
    const float* inputs = (const float*)d_in[0];
    const float* states = (const float*)d_in[1];
    const float* Wi = (const float*)d_in[2];
    const float* Ui = (const float*)d_in[3];
    const float* bi = (const float*)d_in[4];
    const float* Wf = (const float*)d_in[5];
    const float* Uf = (const float*)d_in[6];
    const float* bf = (const float*)d_in[7];
    const float* Wg = (const float*)d_in[8];
    const float* Ug = (const float*)d_in[9];
    const float* bg = (const float*)d_in[10];
    const float* Wc = (const float*)d_in[11];
    const float* Uc = (const float*)d_in[12];
    const float* bc = (const float*)d_in[13];
    float* out = (float*)d_out;

    const size_t need = (AB_ELEMS + 4 * PPLANE) * 2;   // ~37.5 MiB
    if (ws_size >= need) {
        unsigned short* Ab = (unsigned short*)d_ws;
        unsigned short* P  = Ab + AB_ELEMS;
        prep_act<<<1024, 256, 0, stream>>>(inputs, states, Ab);
        gemm_fused<<<dim3(64, 4, 4), 256, 0, stream>>>(Wi, Ui, Wf, Uf,
                                                       Wg, Ug, Wc, Uc, Ab, P);
        combine_kernel<<<BH / (8 * 256), 256, 0, stream>>>(out, P, states,
                                                           bi, bf, bg, bc, 4);
    } else {
        unsigned short* P = (unsigned short*)d_ws;
        const int nz = (ws_size >= 4 * PLANE_BYTES) ? 4 : 2;
        const int KB = 4096 / nz;
        dim3 grid(64, 4, nz);
        gemm_tile<<<grid, 256, 0, stream>>>(inputs, states, Wi, Ui, Wf, Uf,
                                            Wg, Ug, Wc, Uc, P, KB);
        combine_kernel<<<BH / (8 * 256), 256, 0, stream>>>(out, P, states,
                                                           bi, bf, bg, bc, nz);
    }
}